// Round 1
// baseline (438.711 us; speedup 1.0000x reference)
//
#include <hip/hip_runtime.h>
#include <hip/hip_bf16.h>
#include <stdint.h>

#define DIM 2048
#define SEQ 2048
#define BATCH 2
#define NHEADS 32
#define NKV 8
#define HD 64
#define MROWS (BATCH*SEQ)   // 4096
#define KVDIM (2*NKV*HD)    // 1024

typedef __bf16 bf16_t;
typedef __bf16 bf16x8 __attribute__((ext_vector_type(8)));
typedef __bf16 bf16x4 __attribute__((ext_vector_type(4)));
typedef float  f32x4  __attribute__((ext_vector_type(4)));

// ---------------- cast fp32 -> bf16 (vectorized x4) ----------------
__global__ __launch_bounds__(256) void cast_kernel(const float* __restrict__ in,
                                                   bf16_t* __restrict__ out, int n4) {
    int i = blockIdx.x * blockDim.x + threadIdx.x;
    if (i >= n4) return;
    float4 f = ((const float4*)in)[i];
    bf16x4 o;
    o[0] = (bf16_t)f.x; o[1] = (bf16_t)f.y; o[2] = (bf16_t)f.z; o[3] = (bf16_t)f.w;
    ((bf16x4*)out)[i] = o;
}

// ---------------- GEMM: C[M,N] = A[M,K] @ W[N,K]^T + bias, times alpha ----------------
// 128x128 tile, BK=32, 4 waves, each wave 64x64 (4x4 fragments of 16x16).
// Reg-staged LDS (safe baseline; global_load_lds comes in a later round).
template<bool OUT_BF16>
__global__ __launch_bounds__(256) void gemm_bt(
    const bf16_t* __restrict__ A, const bf16_t* __restrict__ W,
    const float* __restrict__ bias, void* __restrict__ Cp,
    int M, int N, int K, float alpha)
{
    __shared__ bf16_t As[128*32];
    __shared__ bf16_t Bs[128*32];
    const int brow = blockIdx.y * 128;
    const int bcol = blockIdx.x * 128;
    const int tid  = threadIdx.x;
    const int lane = tid & 63;
    const int w    = tid >> 6;
    const int wr   = w >> 1, wc = w & 1;
    const int l16  = lane & 15, l4 = lane >> 4;

    f32x4 acc[4][4];
#pragma unroll
    for (int m = 0; m < 4; m++)
#pragma unroll
        for (int n = 0; n < 4; n++) acc[m][n] = (f32x4){0.f, 0.f, 0.f, 0.f};

    const int r  = tid >> 2;        // 0..63 staging row
    const int c8 = (tid & 3) << 3;  // bf16 col offset 0,8,16,24
    const bf16_t* ga = A + (size_t)(brow + r) * K + c8;
    const bf16_t* gb = W + (size_t)(bcol + r) * K + c8;

    const int ard = (wr*64 + l16)*32 + l4*8;  // A-frag LDS elem offset (+m*512)
    const int brd = (wc*64 + l16)*32 + l4*8;  // B-frag LDS elem offset (+n*512)

    for (int kt = 0; kt < K; kt += 32) {
        bf16x8 ra0 = *(const bf16x8*)(ga + kt);
        bf16x8 ra1 = *(const bf16x8*)(ga + (size_t)64*K + kt);
        bf16x8 rb0 = *(const bf16x8*)(gb + kt);
        bf16x8 rb1 = *(const bf16x8*)(gb + (size_t)64*K + kt);
        __syncthreads();
        *(bf16x8*)&As[r*32 + c8]        = ra0;
        *(bf16x8*)&As[(r+64)*32 + c8]   = ra1;
        *(bf16x8*)&Bs[r*32 + c8]        = rb0;
        *(bf16x8*)&Bs[(r+64)*32 + c8]   = rb1;
        __syncthreads();
        bf16x8 af[4], bfr[4];
#pragma unroll
        for (int m = 0; m < 4; m++) af[m]  = *(const bf16x8*)&As[ard + m*16*32];
#pragma unroll
        for (int n = 0; n < 4; n++) bfr[n] = *(const bf16x8*)&Bs[brd + n*16*32];
#pragma unroll
        for (int m = 0; m < 4; m++)
#pragma unroll
            for (int n = 0; n < 4; n++)
                acc[m][n] = __builtin_amdgcn_mfma_f32_16x16x32_bf16(af[m], bfr[n], acc[m][n], 0, 0, 0);
    }

#pragma unroll
    for (int m = 0; m < 4; m++) {
        int row0 = brow + wr*64 + m*16 + l4*4;
#pragma unroll
        for (int n = 0; n < 4; n++) {
            int col = bcol + wc*64 + n*16 + l16;
            float bv = bias[col];
#pragma unroll
            for (int rr = 0; rr < 4; rr++) {
                float v = (acc[m][n][rr] + bv) * alpha;
                if (OUT_BF16) ((bf16_t*)Cp)[(size_t)(row0+rr)*N + col] = (bf16_t)v;
                else          ((float*)Cp)[(size_t)(row0+rr)*N + col]  = v;
            }
        }
    }
}

// ---------------- causal GQA flash attention ----------------
// Grid: (SEQ/64, BATCH*NHEADS). Block 256 = 4 waves, wave w owns q rows [qt*64+w*16, +16).
// Q pre-scaled by 1/sqrt(HD) in projection epilogue.
__global__ __launch_bounds__(256) void attn_kernel(
    const bf16_t* __restrict__ Qm,   // [MROWS, DIM]
    const bf16_t* __restrict__ KVm,  // [MROWS, KVDIM], k at col kvh*64, v at 512+kvh*64
    bf16_t* __restrict__ Am,         // [MROWS, DIM]
    const int* __restrict__ causalp)
{
    __shared__ bf16_t Vt[64*64];       // V^T tile: Vt[d][kvrow]
    __shared__ bf16_t Pl[4*16*64];     // per-wave P tile [16 rows][64 cols]
    const int bh  = blockIdx.y;
    const int b   = bh >> 5;
    const int h   = bh & 31;
    const int kvh = h >> 2;            // GROUPS=4, consecutive repeat
    const int qt  = blockIdx.x;
    const int tid = threadIdx.x;
    const int lane = tid & 63;
    const int w    = tid >> 6;
    const int l16  = lane & 15, l4 = lane >> 4;
    const int causal = *causalp;

    // Q fragments (A-operand), 16 rows x 64 k
    bf16x8 qf[2];
    {
        const bf16_t* qbase = Qm + (size_t)(b*SEQ + qt*64 + w*16 + l16) * DIM + h*HD + l4*8;
        qf[0] = *(const bf16x8*)qbase;
        qf[1] = *(const bf16x8*)(qbase + 32);
    }

    f32x4 o[4];
#pragma unroll
    for (int n = 0; n < 4; n++) o[n] = (f32x4){0.f, 0.f, 0.f, 0.f};
    float mrun[4], srun[4];
#pragma unroll
    for (int rr = 0; rr < 4; rr++) { mrun[rr] = -1e30f; srun[rr] = 0.f; }

    const int nkt = causal ? (qt + 1) : (SEQ/64);
    const int vr  = tid >> 2;          // 0..63 kv row for V staging
    const int vdc = (tid & 3) << 4;    // d offset 0,16,32,48

    for (int kt = 0; kt < nkt; kt++) {
        __syncthreads();   // previous iteration's LDS reads done
        // stage V^T
        {
            const bf16_t* vrow = KVm + (size_t)(b*SEQ + kt*64 + vr) * KVDIM + 512 + kvh*HD + vdc;
            bf16x8 v0 = *(const bf16x8*)vrow;
            bf16x8 v1 = *(const bf16x8*)(vrow + 8);
#pragma unroll
            for (int i = 0; i < 8; i++) Vt[(vdc+i)*64 + vr]   = v0[i];
#pragma unroll
            for (int i = 0; i < 8; i++) Vt[(vdc+8+i)*64 + vr] = v1[i];
        }
        // S = Q K^T  (16 x 64 per wave)
        f32x4 s[4];
#pragma unroll
        for (int n = 0; n < 4; n++) s[n] = (f32x4){0.f, 0.f, 0.f, 0.f};
        const bf16_t* kbase = KVm + (size_t)(b*SEQ + kt*64 + l16) * KVDIM + kvh*HD + l4*8;
#pragma unroll
        for (int n = 0; n < 4; n++)
#pragma unroll
            for (int kk = 0; kk < 2; kk++) {
                bf16x8 kf = *(const bf16x8*)(kbase + (size_t)n*16*KVDIM + kk*32);
                s[n] = __builtin_amdgcn_mfma_f32_16x16x32_bf16(qf[kk], kf, s[n], 0, 0, 0);
            }
        // causal mask on diagonal tile
        if (causal && kt == qt) {
#pragma unroll
            for (int n = 0; n < 4; n++) {
                int col = n*16 + l16;
#pragma unroll
                for (int rr = 0; rr < 4; rr++) {
                    int rowl = w*16 + l4*4 + rr;
                    if (col > rowl) s[n][rr] = -1e30f;
                }
            }
        }
        // online softmax update
        float mnew[4], fac[4], tsum[4];
#pragma unroll
        for (int rr = 0; rr < 4; rr++) {
            float tm = fmaxf(fmaxf(s[0][rr], s[1][rr]), fmaxf(s[2][rr], s[3][rr]));
            tm = fmaxf(tm, __shfl_xor(tm, 1));
            tm = fmaxf(tm, __shfl_xor(tm, 2));
            tm = fmaxf(tm, __shfl_xor(tm, 4));
            tm = fmaxf(tm, __shfl_xor(tm, 8));
            mnew[rr] = fmaxf(mrun[rr], tm);
            fac[rr]  = __expf(mrun[rr] - mnew[rr]);
            mrun[rr] = mnew[rr];
            tsum[rr] = 0.f;
        }
#pragma unroll
        for (int n = 0; n < 4; n++)
#pragma unroll
            for (int rr = 0; rr < 4; rr++) {
                float p = __expf(s[n][rr] - mnew[rr]);
                tsum[rr] += p;
                Pl[w*1024 + (l4*4+rr)*64 + n*16 + l16] = (bf16_t)p;
            }
#pragma unroll
        for (int rr = 0; rr < 4; rr++) {
            float ts = tsum[rr];
            ts += __shfl_xor(ts, 1);
            ts += __shfl_xor(ts, 2);
            ts += __shfl_xor(ts, 4);
            ts += __shfl_xor(ts, 8);
            srun[rr] = srun[rr]*fac[rr] + ts;
        }
#pragma unroll
        for (int n = 0; n < 4; n++)
#pragma unroll
            for (int rr = 0; rr < 4; rr++) o[n][rr] *= fac[rr];
        __syncthreads();   // V^T staged + P visible
        // O += P V
        bf16x8 pa[2];
        pa[0] = *(const bf16x8*)&Pl[w*1024 + l16*64 + l4*8];
        pa[1] = *(const bf16x8*)&Pl[w*1024 + l16*64 + 32 + l4*8];
#pragma unroll
        for (int n = 0; n < 4; n++)
#pragma unroll
            for (int kk = 0; kk < 2; kk++) {
                bf16x8 vf = *(const bf16x8*)&Vt[(n*16+l16)*64 + kk*32 + l4*8];
                o[n] = __builtin_amdgcn_mfma_f32_16x16x32_bf16(pa[kk], vf, o[n], 0, 0, 0);
            }
    }

    // write attention output (bf16) in [MROWS, DIM] layout
#pragma unroll
    for (int n = 0; n < 4; n++) {
        int col = h*HD + n*16 + l16;
#pragma unroll
        for (int rr = 0; rr < 4; rr++) {
            int row = b*SEQ + qt*64 + w*16 + l4*4 + rr;
            float v = o[n][rr] / srun[rr];
            Am[(size_t)row*DIM + col] = (bf16_t)v;
        }
    }
}

// ---------------- launcher ----------------
extern "C" void kernel_launch(void* const* d_in, const int* in_sizes, int n_in,
                              void* d_out, int out_size, void* d_ws, size_t ws_size,
                              hipStream_t stream) {
    const float* x    = (const float*)d_in[0];
    const float* Wq   = (const float*)d_in[1];
    const float* bq   = (const float*)d_in[2];
    const float* Wkv  = (const float*)d_in[3];
    const float* bkv  = (const float*)d_in[4];
    const float* Wo   = (const float*)d_in[5];
    const float* bo   = (const float*)d_in[6];
    const int* causal = (const int*)d_in[7];

    char* ws = (char*)d_ws;
    bf16_t* xb  = (bf16_t*)(ws);                      // 16 MB
    bf16_t* wb  = (bf16_t*)(ws + (16u << 20));        // 8 MB (reused per GEMM)
    bf16_t* Qb  = (bf16_t*)(ws + (24u << 20));        // 16 MB
    bf16_t* KVb = (bf16_t*)(ws + (40u << 20));        // 8 MB
    bf16_t* Ab  = (bf16_t*)(ws + (48u << 20));        // 16 MB  (total 64 MB)

    auto cast = [&](const float* src, bf16_t* dst, int n) {
        int n4 = n / 4;
        cast_kernel<<<(n4 + 255) / 256, 256, 0, stream>>>(src, dst, n4);
    };

    const float scale = 0.125f;  // 1/sqrt(64)

    cast(x, xb, MROWS * DIM);
    cast(Wq, wb, DIM * DIM);
    gemm_bt<true><<<dim3(DIM/128, MROWS/128), 256, 0, stream>>>(
        xb, wb, bq, Qb, MROWS, DIM, DIM, scale);
    cast(Wkv, wb, KVDIM * DIM);
    gemm_bt<true><<<dim3(KVDIM/128, MROWS/128), 256, 0, stream>>>(
        xb, wb, bkv, KVb, MROWS, KVDIM, DIM, 1.0f);
    attn_kernel<<<dim3(SEQ/64, BATCH*NHEADS), 256, 0, stream>>>(Qb, KVb, Ab, causal);
    cast(Wo, wb, DIM * DIM);
    gemm_bt<false><<<dim3(DIM/128, MROWS/128), 256, 0, stream>>>(
        Ab, wb, bo, d_out, MROWS, DIM, DIM, 1.0f);
}